// Round 6
// baseline (1028.696 us; speedup 1.0000x reference)
//
#include <hip/hip_runtime.h>
#include <hip/hip_bf16.h>

#define N_USERS 100000
#define N_ITEMS 50000
#define N_NODES 150000
#define DD 64
#define FF 768
#define N_EDGES_C 4800000
#define BATCH 4096
#define LN_EPS 1e-5f
#define CONTENT_LOSS_W 0.1f

#define NBUCK 147       // ceil(150000/1024) - 1024-node buckets
#define BIN_TILE 4096
#define HIST_BLKS 1200

#define KWIN 24         // 768 / 32 K-windows

typedef __attribute__((ext_vector_type(8))) short short8;
typedef __attribute__((ext_vector_type(4))) float f32x4;

__device__ inline float b2f(unsigned short v) {
    union { unsigned int i; float f; } u;
    u.i = ((unsigned int)v) << 16;
    return u.f;
}
__device__ inline unsigned short f2b(float f) {
    union { float f; unsigned int i; } u; u.f = f;
    unsigned int r = u.i + 0x7fff + ((u.i >> 16) & 1);   // RNE
    return (unsigned short)(r >> 16);
}
__device__ inline short bfc(float f) {
    __hip_bfloat16 h = __float2bfloat16(f);   // compiler emits v_cvt_pk_bf16_f32
    return *reinterpret_cast<short*>(&h);
}

// non-temporal helpers (gfx950 'nt' cache hint - keep streams out of L2)
__device__ inline uint2 ntld_u2(const uint2* p) {
    unsigned long long v = __builtin_nontemporal_load(
        reinterpret_cast<const unsigned long long*>(p));
    uint2 r; r.x = (unsigned)v; r.y = (unsigned)(v >> 32);
    return r;
}
__device__ inline void ntst_u2(uint2* p, uint2 v) {
    unsigned long long q = ((unsigned long long)v.y << 32) | (unsigned long long)v.x;
    __builtin_nontemporal_store(q, reinterpret_cast<unsigned long long*>(p));
}

// ---------------------------------------------------------------------------
// K1: user emb init f32 -> bf16
// ---------------------------------------------------------------------------
__global__ __launch_bounds__(256) void init_users_k(
    const float* __restrict__ ue, unsigned short* __restrict__ emb)
{
    int gid = blockIdx.x * 256 + threadIdx.x;   // N_USERS*DD/4 threads
    size_t base = (size_t)gid * 4;
    float4 v = *reinterpret_cast<const float4*>(ue + base);
    ushort4 o;
    o.x = f2b(v.x); o.y = f2b(v.y); o.z = f2b(v.z); o.w = f2b(v.w);
    *reinterpret_cast<ushort4*>(emb + base) = o;
}

// ---------------------------------------------------------------------------
// Wp (f32 [768][64]) -> bf16 B-fragment-staged layout for mfma 16x16x32.
// bstg index: (((kw*4)+nt)*64 + lane)*8 + e
//   holds Wp[kw*32 + (lane>>4)*8 + e][nt*16 + (lane&15)]
// ---------------------------------------------------------------------------
__global__ __launch_bounds__(256) void wp_stage_k(
    const float* __restrict__ Wp, unsigned short* __restrict__ bstg)
{
    int tid = blockIdx.x * 256 + threadIdx.x;   // 49152 threads
    int e    = tid & 7;
    int lane = (tid >> 3) & 63;
    int nt   = (tid >> 9) & 3;
    int kw   = tid >> 11;
    int k = kw * 32 + ((lane >> 4) << 3) + e;
    int n = nt * 16 + (lane & 15);
    bstg[tid] = (unsigned short)bfc(Wp[k * DD + n]);
}

// ---------------------------------------------------------------------------
// K2: content projection (bf16 MFMA) + f32 gate + combine.  Zero LDS.
// cf is a 153.6 MB one-shot stream -> non-temporal loads.
// ---------------------------------------------------------------------------
__global__ __launch_bounds__(256) void content_mfma_k(
    const float* __restrict__ cf, const unsigned short* __restrict__ bstg,
    const float* __restrict__ bp, const float* __restrict__ wg,
    const float* __restrict__ bg, const float* __restrict__ item_emb,
    float* __restrict__ items_content,
    unsigned short* __restrict__ emb, float* __restrict__ acc_items)
{
    const int wt = blockIdx.x * 4 + (threadIdx.x >> 6);
    if (wt >= N_ITEMS / 16) return;
    const int lane = threadIdx.x & 63;
    const int row0 = wt * 16;

    const int lrow = lane & 15;          // row within tile (A operand)
    const int kgrp = lane >> 4;          // k-chunk 0..3

    const float* aptr = cf + (size_t)(row0 + lrow) * FF + (kgrp << 3);
    const float* wptr = wg + (kgrp << 3);
    const short8* bptr = reinterpret_cast<const short8*>(bstg) + lane;

    f32x4 acc0 = {0.f, 0.f, 0.f, 0.f};
    f32x4 acc1 = {0.f, 0.f, 0.f, 0.f};
    f32x4 acc2 = {0.f, 0.f, 0.f, 0.f};
    f32x4 acc3 = {0.f, 0.f, 0.f, 0.f};
    float gp = 0.f;

    #pragma unroll 4
    for (int kw = 0; kw < KWIN; ++kw) {
        f32x4 a0 = __builtin_nontemporal_load(
            reinterpret_cast<const f32x4*>(aptr + kw * 32));
        f32x4 a1 = __builtin_nontemporal_load(
            reinterpret_cast<const f32x4*>(aptr + kw * 32 + 4));
        float4 w0 = *reinterpret_cast<const float4*>(wptr + kw * 32);
        float4 w1 = *reinterpret_cast<const float4*>(wptr + kw * 32 + 4);

        gp += a0[0] * w0.x + a0[1] * w0.y + a0[2] * w0.z + a0[3] * w0.w;
        gp += a1[0] * w1.x + a1[1] * w1.y + a1[2] * w1.z + a1[3] * w1.w;

        short8 af;
        af[0] = bfc(a0[0]); af[1] = bfc(a0[1]); af[2] = bfc(a0[2]); af[3] = bfc(a0[3]);
        af[4] = bfc(a1[0]); af[5] = bfc(a1[1]); af[6] = bfc(a1[2]); af[7] = bfc(a1[3]);

        const short8* bb = bptr + (size_t)kw * 256;   // (kw*4+nt)*64+lane
        short8 b0 = bb[0];
        short8 b1 = bb[64];
        short8 b2 = bb[128];
        short8 b3 = bb[192];

        acc0 = __builtin_amdgcn_mfma_f32_16x16x32_bf16(af, b0, acc0, 0, 0, 0);
        acc1 = __builtin_amdgcn_mfma_f32_16x16x32_bf16(af, b1, acc1, 0, 0, 0);
        acc2 = __builtin_amdgcn_mfma_f32_16x16x32_bf16(af, b2, acc2, 0, 0, 0);
        acc3 = __builtin_amdgcn_mfma_f32_16x16x32_bf16(af, b3, acc3, 0, 0, 0);
    }

    // gate: lanes {l, l^16, l^32, l^48} hold k-partials for row lane&15
    gp += __shfl_xor(gp, 16);
    gp += __shfl_xor(gp, 32);
    const float g = 1.f / (1.f + __expf(-(gp + bg[0])));

    // epilogue: C layout col=lane&15, row=(lane>>4)*4+reg
    const int rbase = kgrp << 2;
    f32x4 accs[4] = {acc0, acc1, acc2, acc3};
    #pragma unroll
    for (int nt = 0; nt < 4; ++nt) {
        const int col = nt * 16 + lrow;
        const float bpv = bp[col];
        #pragma unroll
        for (int r = 0; r < 4; ++r) {
            const int rit = rbase + r;
            const int row = row0 + rit;
            const float icv = accs[nt][r] + bpv;
            const float gr = __shfl(g, rit);
            const size_t o = (size_t)row * DD + col;
            const float ie = __builtin_nontemporal_load(item_emb + o);
            const float it = (1.f - gr) * ie + gr * icv;
            __builtin_nontemporal_store(icv, items_content + o);
            emb[(size_t)(N_USERS + row) * DD + col] = f2b(it);
            acc_items[o] = it;
        }
    }
}

// ---------------------------------------------------------------------------
// CSR build v3: coarse bucket hist (LDS-privatized, no fine global atomics)
//   -> 147-scan -> bin (write-combined) -> per-bucket scatter that derives
//   per-node cursors in LDS and emits the global cursor array.
// ---------------------------------------------------------------------------
__global__ __launch_bounds__(256) void bucket_hist_k(
    const int* __restrict__ ed, int* __restrict__ bucket_cnt)
{
    __shared__ int lh[NBUCK];
    for (int i = threadIdx.x; i < NBUCK; i += 256) lh[i] = 0;
    __syncthreads();
    const int stride = HIST_BLKS * 256;
    for (int t = blockIdx.x * 256 + threadIdx.x; t < N_EDGES_C / 4; t += stride) {
        int4 d = reinterpret_cast<const int4*>(ed)[t];
        atomicAdd(&lh[d.x >> 10], 1);
        atomicAdd(&lh[d.y >> 10], 1);
        atomicAdd(&lh[d.z >> 10], 1);
        atomicAdd(&lh[d.w >> 10], 1);
    }
    __syncthreads();
    for (int i = threadIdx.x; i < NBUCK; i += 256) {
        int c = lh[i];
        if (c) atomicAdd(&bucket_cnt[i], c);
    }
}

// single block: exclusive scan of 147 bucket counts -> bucket_base[148],
// and init bucket_cursor = base.
__global__ __launch_bounds__(256) void bucket_scan_k(
    const int* __restrict__ bucket_cnt, int* __restrict__ bucket_base,
    int* __restrict__ bucket_cursor)
{
    __shared__ int sdata[256];
    int t = threadIdx.x;
    int v = (t < NBUCK) ? bucket_cnt[t] : 0;
    sdata[t] = v;
    __syncthreads();
    for (int off = 1; off < 256; off <<= 1) {
        int x = (t >= off) ? sdata[t - off] : 0;
        __syncthreads();
        sdata[t] += x;
        __syncthreads();
    }
    if (t < NBUCK) {
        int b = sdata[t] - v;   // exclusive
        bucket_base[t] = b;
        bucket_cursor[t] = b;
    }
    if (t == NBUCK - 1) bucket_base[NBUCK] = sdata[t];   // == N_EDGES_C
}

// Pass A: tile-sort edges into 147 coarse buckets with LDS write combining.
// binned entry: x = (src<<10)|(dst&1023), y = weight bits
// copy-out uses a per-staged-entry bucket-id byte (no binary search).
__global__ __launch_bounds__(256) void bin_k(
    const int* __restrict__ ed, const int* __restrict__ es,
    const float* __restrict__ ew, int* __restrict__ bucket_cursor,
    uint2* __restrict__ binned)
{
    __shared__ uint2 stage[BIN_TILE];        // 32 KB
    __shared__ unsigned char bktb[BIN_TILE]; // 4 KB bucket id per staged slot
    __shared__ int h[NBUCK];                 // hist, then running cursor
    __shared__ int o[NBUCK];                 // exclusive offsets
    __shared__ int gbase[NBUCK];
    __shared__ int scanbuf[256];

    const int t = threadIdx.x;
    const int base = blockIdx.x * BIN_TILE;
    const int cnt = min(BIN_TILE, N_EDGES_C - base);

    for (int i = t; i < NBUCK; i += 256) h[i] = 0;
    __syncthreads();

    int ld[16]; int ls[16]; float lw[16]; int lb[16];
    #pragma unroll
    for (int k = 0; k < 16; ++k) {
        int i = t + k * 256;
        if (i < cnt) {
            int d = __builtin_nontemporal_load(ed + base + i);
            ld[k] = d;
            ls[k] = __builtin_nontemporal_load(es + base + i);
            lw[k] = __builtin_nontemporal_load(ew + base + i);
            int b = d >> 10;
            lb[k] = b;
            atomicAdd(&h[b], 1);
        } else lb[k] = -1;
    }
    __syncthreads();

    // exclusive scan of h -> o (NBUCK <= 256)
    {
        int v = (t < NBUCK) ? h[t] : 0;
        scanbuf[t] = v;
        __syncthreads();
        for (int off = 1; off < 256; off <<= 1) {
            int x = (t >= off) ? scanbuf[t - off] : 0;
            __syncthreads();
            scanbuf[t] += x;
            __syncthreads();
        }
        if (t < NBUCK) o[t] = scanbuf[t] - v;
    }
    __syncthreads();

    if (t < NBUCK) h[t] = o[t];   // running cursors
    __syncthreads();

    #pragma unroll
    for (int k = 0; k < 16; ++k) {
        if (lb[k] >= 0) {
            int p = atomicAdd(&h[lb[k]], 1);
            unsigned key = ((unsigned)ls[k] << 10) | (unsigned)(ld[k] & 1023);
            stage[p] = make_uint2(key, __float_as_uint(lw[k]));
            bktb[p] = (unsigned char)lb[k];
        }
    }
    __syncthreads();

    // reserve contiguous global space per bucket (h now = end offsets)
    if (t < NBUCK) {
        int c = h[t] - o[t];
        gbase[t] = (c > 0) ? atomicAdd(&bucket_cursor[t], c) : 0;
    }
    __syncthreads();

    // copy out, coalesced within bucket segments; O(1) bucket lookup
    for (int i = t; i < cnt; i += 256) {
        int b = bktb[i];
        ntst_u2(&binned[gbase[b] + (i - o[b])], stage[i]);
    }
}

// Pass B: one block owns one 1024-node bucket.  Builds the per-node
// histogram + scan from its own binned segment (emitting cursor[] as a
// by-product), then scatters to final CSR slots.
__global__ __launch_bounds__(1024) void scatter_k(
    const uint2* __restrict__ binned, const int* __restrict__ bucket_base,
    int* __restrict__ cursor, uint2* __restrict__ adj)
{
    __shared__ int lh[1024];     // hist -> running cursor
    __shared__ int sdata[1024];  // scan workspace
    const int b = blockIdx.x;
    const int t = threadIdx.x;
    const int nb = b << 10;
    const int s0 = bucket_base[b];
    const int s1 = bucket_base[b + 1];

    lh[t] = 0;
    __syncthreads();
    for (int i = s0 + t; i < s1; i += 1024)
        atomicAdd(&lh[binned[i].x & 1023u], 1);
    __syncthreads();

    // exclusive scan of lh over 1024
    int v = lh[t];
    sdata[t] = v;
    __syncthreads();
    for (int off = 1; off < 1024; off <<= 1) {
        int x = (t >= off) ? sdata[t - off] : 0;
        __syncthreads();
        sdata[t] += x;
        __syncthreads();
    }
    const int start = s0 + sdata[t] - v;   // global CSR start for node nb+t
    if (nb + t < N_NODES) cursor[nb + t] = start;
    lh[t] = start;                          // running cursor
    __syncthreads();

    for (int i = s0 + t; i < s1; i += 1024) {
        uint2 e = binned[i];
        int ln = (int)(e.x & 1023u);
        int p = atomicAdd(&lh[ln], 1);
        ntst_u2(&adj[p], make_uint2(e.x >> 10, e.y));
    }
}

// ---------------------------------------------------------------------------
// K3: fused aggregate + layernorm + residual (bf16 emb state)
// 4 edge-slot groups of 16 lanes; lane covers 4 cols (ushort4 per gather).
// adj + acc_items are one-shot streams -> non-temporal, preserving L2 for
// the 19.2 MB emb table (the only data with reuse).
// ---------------------------------------------------------------------------
__global__ __launch_bounds__(256) void agg_ln_k(
    const unsigned short* __restrict__ emb_in,
    unsigned short* __restrict__ emb_out,
    float* __restrict__ acc_items,
    const int* __restrict__ cursor, const uint2* __restrict__ adj)
{
    const int n = blockIdx.x * 4 + (threadIdx.x >> 6);   // 37500 blocks exact
    const int lane = threadIdx.x & 63;
    const int g = lane >> 4;          // edge-slot group 0..3
    const int q = lane & 15;          // column quad: cols 4q..4q+3
    const int qo = q << 2;

    const int beg = cursor[n];
    const int end = (n == N_NODES - 1) ? N_EDGES_C : cursor[n + 1];

    float a0 = 0.f, a1 = 0.f, a2 = 0.f, a3 = 0.f;

    int j = beg;
    // main: 32 edges per iteration (8 chunks of 4)
    for (; j + 31 < end; j += 32) {
        uint2 e0 = ntld_u2(&adj[j      + g]);
        uint2 e1 = ntld_u2(&adj[j +  4 + g]);
        uint2 e2 = ntld_u2(&adj[j +  8 + g]);
        uint2 e3 = ntld_u2(&adj[j + 12 + g]);
        uint2 e4 = ntld_u2(&adj[j + 16 + g]);
        uint2 e5 = ntld_u2(&adj[j + 20 + g]);
        uint2 e6 = ntld_u2(&adj[j + 24 + g]);
        uint2 e7 = ntld_u2(&adj[j + 28 + g]);
        ushort4 r0 = *reinterpret_cast<const ushort4*>(emb_in + (size_t)e0.x * DD + qo);
        ushort4 r1 = *reinterpret_cast<const ushort4*>(emb_in + (size_t)e1.x * DD + qo);
        ushort4 r2 = *reinterpret_cast<const ushort4*>(emb_in + (size_t)e2.x * DD + qo);
        ushort4 r3 = *reinterpret_cast<const ushort4*>(emb_in + (size_t)e3.x * DD + qo);
        ushort4 r4 = *reinterpret_cast<const ushort4*>(emb_in + (size_t)e4.x * DD + qo);
        ushort4 r5 = *reinterpret_cast<const ushort4*>(emb_in + (size_t)e5.x * DD + qo);
        ushort4 r6 = *reinterpret_cast<const ushort4*>(emb_in + (size_t)e6.x * DD + qo);
        ushort4 r7 = *reinterpret_cast<const ushort4*>(emb_in + (size_t)e7.x * DD + qo);
        float w0 = __uint_as_float(e0.y), w1 = __uint_as_float(e1.y);
        float w2 = __uint_as_float(e2.y), w3 = __uint_as_float(e3.y);
        float w4 = __uint_as_float(e4.y), w5 = __uint_as_float(e5.y);
        float w6 = __uint_as_float(e6.y), w7 = __uint_as_float(e7.y);
        a0 += w0 * b2f(r0.x); a1 += w0 * b2f(r0.y); a2 += w0 * b2f(r0.z); a3 += w0 * b2f(r0.w);
        a0 += w1 * b2f(r1.x); a1 += w1 * b2f(r1.y); a2 += w1 * b2f(r1.z); a3 += w1 * b2f(r1.w);
        a0 += w2 * b2f(r2.x); a1 += w2 * b2f(r2.y); a2 += w2 * b2f(r2.z); a3 += w2 * b2f(r2.w);
        a0 += w3 * b2f(r3.x); a1 += w3 * b2f(r3.y); a2 += w3 * b2f(r3.z); a3 += w3 * b2f(r3.w);
        a0 += w4 * b2f(r4.x); a1 += w4 * b2f(r4.y); a2 += w4 * b2f(r4.z); a3 += w4 * b2f(r4.w);
        a0 += w5 * b2f(r5.x); a1 += w5 * b2f(r5.y); a2 += w5 * b2f(r5.z); a3 += w5 * b2f(r5.w);
        a0 += w6 * b2f(r6.x); a1 += w6 * b2f(r6.y); a2 += w6 * b2f(r6.z); a3 += w6 * b2f(r6.w);
        a0 += w7 * b2f(r7.x); a1 += w7 * b2f(r7.y); a2 += w7 * b2f(r7.z); a3 += w7 * b2f(r7.w);
    }
    // 16-edge chunk
    if (j + 15 < end) {
        uint2 e0 = ntld_u2(&adj[j + g]);
        uint2 e1 = ntld_u2(&adj[j + 4 + g]);
        uint2 e2 = ntld_u2(&adj[j + 8 + g]);
        uint2 e3 = ntld_u2(&adj[j + 12 + g]);
        ushort4 r0 = *reinterpret_cast<const ushort4*>(emb_in + (size_t)e0.x * DD + qo);
        ushort4 r1 = *reinterpret_cast<const ushort4*>(emb_in + (size_t)e1.x * DD + qo);
        ushort4 r2 = *reinterpret_cast<const ushort4*>(emb_in + (size_t)e2.x * DD + qo);
        ushort4 r3 = *reinterpret_cast<const ushort4*>(emb_in + (size_t)e3.x * DD + qo);
        float w0 = __uint_as_float(e0.y), w1 = __uint_as_float(e1.y);
        float w2 = __uint_as_float(e2.y), w3 = __uint_as_float(e3.y);
        a0 += w0 * b2f(r0.x); a1 += w0 * b2f(r0.y); a2 += w0 * b2f(r0.z); a3 += w0 * b2f(r0.w);
        a0 += w1 * b2f(r1.x); a1 += w1 * b2f(r1.y); a2 += w1 * b2f(r1.z); a3 += w1 * b2f(r1.w);
        a0 += w2 * b2f(r2.x); a1 += w2 * b2f(r2.y); a2 += w2 * b2f(r2.z); a3 += w2 * b2f(r2.w);
        a0 += w3 * b2f(r3.x); a1 += w3 * b2f(r3.y); a2 += w3 * b2f(r3.z); a3 += w3 * b2f(r3.w);
        j += 16;
    }
    // 4-edge chunks
    for (; j + 3 < end; j += 4) {
        uint2 e = ntld_u2(&adj[j + g]);
        ushort4 r = *reinterpret_cast<const ushort4*>(emb_in + (size_t)e.x * DD + qo);
        float w = __uint_as_float(e.y);
        a0 += w * b2f(r.x); a1 += w * b2f(r.y); a2 += w * b2f(r.z); a3 += w * b2f(r.w);
    }
    // tail (<4 edges): group g handles edge j+g if in range
    if (g < end - j) {
        uint2 e = ntld_u2(&adj[j + g]);
        ushort4 r = *reinterpret_cast<const ushort4*>(emb_in + (size_t)e.x * DD + qo);
        float w = __uint_as_float(e.y);
        a0 += w * b2f(r.x); a1 += w * b2f(r.y); a2 += w * b2f(r.z); a3 += w * b2f(r.w);
    }

    // cross-group reduce: lanes {l, l^16, l^32, l^48} hold disjoint edge subsets
    a0 += __shfl_xor(a0, 16); a0 += __shfl_xor(a0, 32);
    a1 += __shfl_xor(a1, 16); a1 += __shfl_xor(a1, 32);
    a2 += __shfl_xor(a2, 16); a2 += __shfl_xor(a2, 32);
    a3 += __shfl_xor(a3, 16); a3 += __shfl_xor(a3, 32);

    // LN reductions over the 16 column-quads (replicated across groups)
    float s = a0 + a1 + a2 + a3;
    s += __shfl_xor(s, 1); s += __shfl_xor(s, 2);
    s += __shfl_xor(s, 4); s += __shfl_xor(s, 8);
    const float m = s * (1.f / 64.f);
    const float d0 = a0 - m, d1 = a1 - m, d2 = a2 - m, d3 = a3 - m;
    float vv = d0 * d0 + d1 * d1 + d2 * d2 + d3 * d3;
    vv += __shfl_xor(vv, 1); vv += __shfl_xor(vv, 2);
    vv += __shfl_xor(vv, 4); vv += __shfl_xor(vv, 8);
    const float rstd = rsqrtf(vv * (1.f / 64.f) + LN_EPS);

    // residual + write (group 0 only: avoids 4x duplicate stores)
    if (g == 0) {
        const size_t o = (size_t)n * DD + qo;
        ushort4 own = *reinterpret_cast<const ushort4*>(emb_in + o);
        float e0 = d0 * rstd + b2f(own.x);
        float e1 = d1 * rstd + b2f(own.y);
        float e2 = d2 * rstd + b2f(own.z);
        float e3 = d3 * rstd + b2f(own.w);
        ushort4 ob;
        ob.x = f2b(e0); ob.y = f2b(e1); ob.z = f2b(e2); ob.w = f2b(e3);
        *reinterpret_cast<ushort4*>(emb_out + o) = ob;
        if (n >= N_USERS) {
            f32x4* ap = reinterpret_cast<f32x4*>(
                acc_items + (size_t)(n - N_USERS) * DD + qo);
            f32x4 v = __builtin_nontemporal_load(ap);
            v[0] += e0; v[1] += e1; v[2] += e2; v[3] += e3;
            __builtin_nontemporal_store(v, ap);
        }
    }
}

// ---------------------------------------------------------------------------
// K4: accumulate sampled rows directly into out
// ---------------------------------------------------------------------------
__global__ __launch_bounds__(256) void gather_acc_k(
    const int* __restrict__ users, const int* __restrict__ pos,
    const int* __restrict__ neg, const unsigned short* __restrict__ emb_state,
    float* __restrict__ out, int init)
{
    int gid = blockIdx.x * 256 + threadIdx.x;   // 3*BATCH*DD = 786432
    int part = gid / (BATCH * DD);
    int r = gid - part * (BATCH * DD);
    int b = r >> 6, c = r & 63;
    int node;
    if (part == 0)      node = users[b];
    else if (part == 1) node = N_USERS + pos[b];
    else                node = N_USERS + neg[b];
    float v = b2f(emb_state[(size_t)node * DD + c]);
    if (init) out[gid] = v;
    else      out[gid] += v;
}

// ---------------------------------------------------------------------------
// K5: content loss
// ---------------------------------------------------------------------------
__global__ __launch_bounds__(256) void loss_k(
    const float* __restrict__ acc_items, const float* __restrict__ ic,
    float* __restrict__ loss_slot)
{
    const int total = N_ITEMS * DD;
    int stride = gridDim.x * 256;
    float p = 0.f;
    for (int i = blockIdx.x * 256 + threadIdx.x; i < total; i += stride) {
        float d = __builtin_nontemporal_load(acc_items + i) * 0.25f
                - __builtin_nontemporal_load(ic + i);
        p += d * d;
    }
    #pragma unroll
    for (int off = 32; off; off >>= 1) p += __shfl_xor(p, off);
    __shared__ float red[4];
    if ((threadIdx.x & 63) == 0) red[threadIdx.x >> 6] = p;
    __syncthreads();
    if (threadIdx.x == 0)
        atomicAdd(loss_slot, red[0] + red[1] + red[2] + red[3]);
}

// ---------------------------------------------------------------------------
// K6: out *= 0.25 ; write loss element
// ---------------------------------------------------------------------------
__global__ __launch_bounds__(256) void final_out_k(
    const float* __restrict__ loss_slot, float* __restrict__ out)
{
    int gid = blockIdx.x * 256 + threadIdx.x;
    out[gid] *= 0.25f;
    if (gid == 0)
        out[3 * BATCH * DD] =
            loss_slot[0] * (CONTENT_LOSS_W / (float)(N_ITEMS * DD));
}

// ---------------------------------------------------------------------------
extern "C" void kernel_launch(void* const* d_in, const int* in_sizes, int n_in,
                              void* d_out, int out_size, void* d_ws, size_t ws_size,
                              hipStream_t stream)
{
    const int* users = (const int*)d_in[0];
    const int* pos   = (const int*)d_in[1];
    const int* neg   = (const int*)d_in[2];
    const int* es    = (const int*)d_in[3];
    const int* ed    = (const int*)d_in[4];
    const float* ew  = (const float*)d_in[5];
    const float* ue  = (const float*)d_in[6];
    const float* ie  = (const float*)d_in[7];
    const float* cf  = (const float*)d_in[8];
    const float* Wp  = (const float*)d_in[9];
    const float* bp  = (const float*)d_in[10];
    const float* wg  = (const float*)d_in[11];
    const float* bg  = (const float*)d_in[12];
    float* out = (float*)d_out;

    // ---- workspace layout (~103 MB) ----
    unsigned short* embA = (unsigned short*)d_ws;             // 19.2 MB
    unsigned short* embB = embA + (size_t)N_NODES * DD;       // 19.2 MB
    float* acc_items = (float*)(embB + (size_t)N_NODES * DD); // 12.8 MB
    float* ic        = acc_items + (size_t)N_ITEMS * DD;      // 12.8 MB
    float* loss_slot = ic + (size_t)N_ITEMS * DD;             // 64 B
    int*   cursor    = (int*)(loss_slot + 16);                // 600 KB
    int*   bucket_cnt    = cursor + 150016;                   // 1 KB
    int*   bucket_base   = bucket_cnt + 256;                  // 1 KB
    int*   bucket_cursor = bucket_base + 256;                 // 1 KB
    uint2* adj       = (uint2*)(bucket_cursor + 256);         // 38.4 MB
    // binned scratch overlaps embB..ic (dead after scatter_k; CSR build
    // runs BEFORE content path / embB use). 38.4 MB <= 44.8 MB region.
    uint2* binned    = (uint2*)embB;
    // bstg (96 KB) parked in embA's USER region: content_mfma_k reads it
    // while writing only the ITEM region of embA; init_users_k overwrites
    // it afterwards (bstg dead by then). Zero workspace growth.
    unsigned short* bstg = embA;

    hipMemsetAsync(bucket_cnt, 0, 256 * sizeof(int), stream);
    hipMemsetAsync(loss_slot, 0, sizeof(float), stream);

    // ---- CSR build (no fine-grained global atomics anywhere) ----
    bucket_hist_k<<<HIST_BLKS, 256, 0, stream>>>(ed, bucket_cnt);
    bucket_scan_k<<<1, 256, 0, stream>>>(bucket_cnt, bucket_base, bucket_cursor);
    bin_k<<<(N_EDGES_C + BIN_TILE - 1) / BIN_TILE, 256, 0, stream>>>(
        ed, es, ew, bucket_cursor, binned);
    scatter_k<<<NBUCK, 1024, 0, stream>>>(binned, bucket_base, cursor, adj);

    // ---- content path (MFMA), then user init overwrites bstg ----
    wp_stage_k<<<192, 256, 0, stream>>>(Wp, bstg);
    content_mfma_k<<<(N_ITEMS / 16 + 3) / 4, 256, 0, stream>>>(
        cf, bstg, bp, wg, bg, ie, ic, embA, acc_items);
    init_users_k<<<(N_USERS * DD / 4) / 256, 256, 0, stream>>>(ue, embA);
    gather_acc_k<<<3 * BATCH * DD / 256, 256, 0, stream>>>(users, pos, neg,
                                                           embA, out, 1);

    // 3 propagation layers, ping-pong
    unsigned short* cur = embA;
    unsigned short* nxt = embB;
    for (int l = 0; l < 3; ++l) {
        agg_ln_k<<<N_NODES / 4, 256, 0, stream>>>(cur, nxt, acc_items,
                                                  cursor, adj);
        gather_acc_k<<<3 * BATCH * DD / 256, 256, 0, stream>>>(users, pos, neg,
                                                               nxt, out, 0);
        unsigned short* t = cur; cur = nxt; nxt = t;
    }

    loss_k<<<2048, 256, 0, stream>>>(acc_items, ic, loss_slot);
    final_out_k<<<3 * BATCH * DD / 256, 256, 0, stream>>>(loss_slot, out);
}

// Round 7
// 882.926 us; speedup vs baseline: 1.1651x; 1.1651x over previous
//
#include <hip/hip_runtime.h>
#include <hip/hip_bf16.h>

#define N_USERS 100000
#define N_ITEMS 50000
#define N_NODES 150000
#define DD 64
#define FF 768
#define N_EDGES_C 4800000
#define BATCH 4096
#define LN_EPS 1e-5f
#define CONTENT_LOSS_W 0.1f

#define NBUCK 147       // ceil(150000/1024) - 1024-node buckets
#define BIN_TILE 4096
#define HIST_BLKS 1200

#define KWIN 24         // 768 / 32 K-windows

typedef __attribute__((ext_vector_type(8))) short short8;
typedef __attribute__((ext_vector_type(4))) float f32x4;

__device__ inline float b2f(unsigned short v) {
    union { unsigned int i; float f; } u;
    u.i = ((unsigned int)v) << 16;
    return u.f;
}
__device__ inline unsigned short f2b(float f) {
    union { float f; unsigned int i; } u; u.f = f;
    unsigned int r = u.i + 0x7fff + ((u.i >> 16) & 1);   // RNE
    return (unsigned short)(r >> 16);
}
__device__ inline short bfc(float f) {
    __hip_bfloat16 h = __float2bfloat16(f);   // compiler emits v_cvt_pk_bf16_f32
    return *reinterpret_cast<short*>(&h);
}

// non-temporal LOAD helper (gfx950 'nt'): safe for single-use streams.
// NOTE (R5 lesson): nt STORES on scattered/partial-line data defeat L2
// write-combining (scatter_k 196us, 4x write amplification) - never again.
__device__ inline uint2 ntld_u2(const uint2* p) {
    unsigned long long v = __builtin_nontemporal_load(
        reinterpret_cast<const unsigned long long*>(p));
    uint2 r; r.x = (unsigned)v; r.y = (unsigned)(v >> 32);
    return r;
}

// ---------------------------------------------------------------------------
// K1: user emb init f32 -> bf16
// ---------------------------------------------------------------------------
__global__ __launch_bounds__(256) void init_users_k(
    const float* __restrict__ ue, unsigned short* __restrict__ emb)
{
    int gid = blockIdx.x * 256 + threadIdx.x;   // N_USERS*DD/4 threads
    size_t base = (size_t)gid * 4;
    float4 v = *reinterpret_cast<const float4*>(ue + base);
    ushort4 o;
    o.x = f2b(v.x); o.y = f2b(v.y); o.z = f2b(v.z); o.w = f2b(v.w);
    *reinterpret_cast<ushort4*>(emb + base) = o;
}

// ---------------------------------------------------------------------------
// Wp (f32 [768][64]) -> bf16 B-fragment-staged layout for mfma 16x16x32.
// ---------------------------------------------------------------------------
__global__ __launch_bounds__(256) void wp_stage_k(
    const float* __restrict__ Wp, unsigned short* __restrict__ bstg)
{
    int tid = blockIdx.x * 256 + threadIdx.x;   // 49152 threads
    int e    = tid & 7;
    int lane = (tid >> 3) & 63;
    int nt   = (tid >> 9) & 3;
    int kw   = tid >> 11;
    int k = kw * 32 + ((lane >> 4) << 3) + e;
    int n = nt * 16 + (lane & 15);
    bstg[tid] = (unsigned short)bfc(Wp[k * DD + n]);
}

// ---------------------------------------------------------------------------
// K2: content projection (bf16 MFMA) + f32 gate + combine.  Zero LDS.
// cf is a 153.6 MB one-shot stream -> non-temporal loads.
// ---------------------------------------------------------------------------
__global__ __launch_bounds__(256) void content_mfma_k(
    const float* __restrict__ cf, const unsigned short* __restrict__ bstg,
    const float* __restrict__ bp, const float* __restrict__ wg,
    const float* __restrict__ bg, const float* __restrict__ item_emb,
    float* __restrict__ items_content,
    unsigned short* __restrict__ emb, float* __restrict__ acc_items)
{
    const int wt = blockIdx.x * 4 + (threadIdx.x >> 6);
    if (wt >= N_ITEMS / 16) return;
    const int lane = threadIdx.x & 63;
    const int row0 = wt * 16;

    const int lrow = lane & 15;          // row within tile (A operand)
    const int kgrp = lane >> 4;          // k-chunk 0..3

    const float* aptr = cf + (size_t)(row0 + lrow) * FF + (kgrp << 3);
    const float* wptr = wg + (kgrp << 3);
    const short8* bptr = reinterpret_cast<const short8*>(bstg) + lane;

    f32x4 acc0 = {0.f, 0.f, 0.f, 0.f};
    f32x4 acc1 = {0.f, 0.f, 0.f, 0.f};
    f32x4 acc2 = {0.f, 0.f, 0.f, 0.f};
    f32x4 acc3 = {0.f, 0.f, 0.f, 0.f};
    float gp = 0.f;

    #pragma unroll 4
    for (int kw = 0; kw < KWIN; ++kw) {
        f32x4 a0 = __builtin_nontemporal_load(
            reinterpret_cast<const f32x4*>(aptr + kw * 32));
        f32x4 a1 = __builtin_nontemporal_load(
            reinterpret_cast<const f32x4*>(aptr + kw * 32 + 4));
        float4 w0 = *reinterpret_cast<const float4*>(wptr + kw * 32);
        float4 w1 = *reinterpret_cast<const float4*>(wptr + kw * 32 + 4);

        gp += a0[0] * w0.x + a0[1] * w0.y + a0[2] * w0.z + a0[3] * w0.w;
        gp += a1[0] * w1.x + a1[1] * w1.y + a1[2] * w1.z + a1[3] * w1.w;

        short8 af;
        af[0] = bfc(a0[0]); af[1] = bfc(a0[1]); af[2] = bfc(a0[2]); af[3] = bfc(a0[3]);
        af[4] = bfc(a1[0]); af[5] = bfc(a1[1]); af[6] = bfc(a1[2]); af[7] = bfc(a1[3]);

        const short8* bb = bptr + (size_t)kw * 256;   // (kw*4+nt)*64+lane
        short8 b0 = bb[0];
        short8 b1 = bb[64];
        short8 b2 = bb[128];
        short8 b3 = bb[192];

        acc0 = __builtin_amdgcn_mfma_f32_16x16x32_bf16(af, b0, acc0, 0, 0, 0);
        acc1 = __builtin_amdgcn_mfma_f32_16x16x32_bf16(af, b1, acc1, 0, 0, 0);
        acc2 = __builtin_amdgcn_mfma_f32_16x16x32_bf16(af, b2, acc2, 0, 0, 0);
        acc3 = __builtin_amdgcn_mfma_f32_16x16x32_bf16(af, b3, acc3, 0, 0, 0);
    }

    // gate: lanes {l, l^16, l^32, l^48} hold k-partials for row lane&15
    gp += __shfl_xor(gp, 16);
    gp += __shfl_xor(gp, 32);
    const float g = 1.f / (1.f + __expf(-(gp + bg[0])));

    // epilogue: C layout col=lane&15, row=(lane>>4)*4+reg
    const int rbase = kgrp << 2;
    f32x4 accs[4] = {acc0, acc1, acc2, acc3};
    #pragma unroll
    for (int nt = 0; nt < 4; ++nt) {
        const int col = nt * 16 + lrow;
        const float bpv = bp[col];
        #pragma unroll
        for (int r = 0; r < 4; ++r) {
            const int rit = rbase + r;
            const int row = row0 + rit;
            const float icv = accs[nt][r] + bpv;
            const float gr = __shfl(g, rit);
            const size_t o = (size_t)row * DD + col;
            const float ie = __builtin_nontemporal_load(item_emb + o);
            const float it = (1.f - gr) * ie + gr * icv;
            items_content[o] = icv;
            emb[(size_t)(N_USERS + row) * DD + col] = f2b(it);
            acc_items[o] = it;
        }
    }
}

// ---------------------------------------------------------------------------
// CSR build v3: coarse bucket hist (LDS-privatized, no fine global atomics)
// ---------------------------------------------------------------------------
__global__ __launch_bounds__(256) void bucket_hist_k(
    const int* __restrict__ ed, int* __restrict__ bucket_cnt)
{
    __shared__ int lh[NBUCK];
    for (int i = threadIdx.x; i < NBUCK; i += 256) lh[i] = 0;
    __syncthreads();
    const int stride = HIST_BLKS * 256;
    for (int t = blockIdx.x * 256 + threadIdx.x; t < N_EDGES_C / 4; t += stride) {
        int4 d = reinterpret_cast<const int4*>(ed)[t];
        atomicAdd(&lh[d.x >> 10], 1);
        atomicAdd(&lh[d.y >> 10], 1);
        atomicAdd(&lh[d.z >> 10], 1);
        atomicAdd(&lh[d.w >> 10], 1);
    }
    __syncthreads();
    for (int i = threadIdx.x; i < NBUCK; i += 256) {
        int c = lh[i];
        if (c) atomicAdd(&bucket_cnt[i], c);
    }
}

// single block: exclusive scan of 147 bucket counts -> bucket_base[148],
// and init bucket_cursor = base.
__global__ __launch_bounds__(256) void bucket_scan_k(
    const int* __restrict__ bucket_cnt, int* __restrict__ bucket_base,
    int* __restrict__ bucket_cursor)
{
    __shared__ int sdata[256];
    int t = threadIdx.x;
    int v = (t < NBUCK) ? bucket_cnt[t] : 0;
    sdata[t] = v;
    __syncthreads();
    for (int off = 1; off < 256; off <<= 1) {
        int x = (t >= off) ? sdata[t - off] : 0;
        __syncthreads();
        sdata[t] += x;
        __syncthreads();
    }
    if (t < NBUCK) {
        int b = sdata[t] - v;   // exclusive
        bucket_base[t] = b;
        bucket_cursor[t] = b;
    }
    if (t == NBUCK - 1) bucket_base[NBUCK] = sdata[t];   // == N_EDGES_C
}

// Pass A: tile-sort edges into 147 coarse buckets with LDS write combining.
// binned entry: x = (src<<10)|(dst&1023), y = weight bits
// copy-out uses a per-staged-entry bucket-id byte (no binary search).
// PLAIN stores (L2 write-combining essential - R5 lesson).
__global__ __launch_bounds__(256) void bin_k(
    const int* __restrict__ ed, const int* __restrict__ es,
    const float* __restrict__ ew, int* __restrict__ bucket_cursor,
    uint2* __restrict__ binned)
{
    __shared__ uint2 stage[BIN_TILE];        // 32 KB
    __shared__ unsigned char bktb[BIN_TILE]; // 4 KB bucket id per staged slot
    __shared__ int h[NBUCK];                 // hist, then running cursor
    __shared__ int o[NBUCK];                 // exclusive offsets
    __shared__ int gbase[NBUCK];
    __shared__ int scanbuf[256];

    const int t = threadIdx.x;
    const int base = blockIdx.x * BIN_TILE;
    const int cnt = min(BIN_TILE, N_EDGES_C - base);

    for (int i = t; i < NBUCK; i += 256) h[i] = 0;
    __syncthreads();

    int ld[16]; int ls[16]; float lw[16]; int lb[16];
    #pragma unroll
    for (int k = 0; k < 16; ++k) {
        int i = t + k * 256;
        if (i < cnt) {
            int d = __builtin_nontemporal_load(ed + base + i);
            ld[k] = d;
            ls[k] = __builtin_nontemporal_load(es + base + i);
            lw[k] = __builtin_nontemporal_load(ew + base + i);
            int b = d >> 10;
            lb[k] = b;
            atomicAdd(&h[b], 1);
        } else lb[k] = -1;
    }
    __syncthreads();

    // exclusive scan of h -> o (NBUCK <= 256)
    {
        int v = (t < NBUCK) ? h[t] : 0;
        scanbuf[t] = v;
        __syncthreads();
        for (int off = 1; off < 256; off <<= 1) {
            int x = (t >= off) ? scanbuf[t - off] : 0;
            __syncthreads();
            scanbuf[t] += x;
            __syncthreads();
        }
        if (t < NBUCK) o[t] = scanbuf[t] - v;
    }
    __syncthreads();

    if (t < NBUCK) h[t] = o[t];   // running cursors
    __syncthreads();

    #pragma unroll
    for (int k = 0; k < 16; ++k) {
        if (lb[k] >= 0) {
            int p = atomicAdd(&h[lb[k]], 1);
            unsigned key = ((unsigned)ls[k] << 10) | (unsigned)(ld[k] & 1023);
            stage[p] = make_uint2(key, __float_as_uint(lw[k]));
            bktb[p] = (unsigned char)lb[k];
        }
    }
    __syncthreads();

    // reserve contiguous global space per bucket (h now = end offsets)
    if (t < NBUCK) {
        int c = h[t] - o[t];
        gbase[t] = (c > 0) ? atomicAdd(&bucket_cursor[t], c) : 0;
    }
    __syncthreads();

    // copy out, coalesced within bucket segments; O(1) bucket lookup
    for (int i = t; i < cnt; i += 256) {
        int b = bktb[i];
        binned[gbase[b] + (i - o[b])] = stage[i];
    }
}

// Pass B: one block owns one 1024-node bucket.  Builds the per-node
// histogram + scan from its own binned segment (emitting cursor[] as a
// by-product), then scatters to final CSR slots.  PLAIN adj stores so the
// owning XCD's L2 combines them (R5 lesson: nt here = 4x write amp).
__global__ __launch_bounds__(1024) void scatter_k(
    const uint2* __restrict__ binned, const int* __restrict__ bucket_base,
    int* __restrict__ cursor, uint2* __restrict__ adj)
{
    __shared__ int lh[1024];     // hist -> running cursor
    __shared__ int sdata[1024];  // scan workspace
    const int b = blockIdx.x;
    const int t = threadIdx.x;
    const int nb = b << 10;
    const int s0 = bucket_base[b];
    const int s1 = bucket_base[b + 1];

    lh[t] = 0;
    __syncthreads();
    for (int i = s0 + t; i < s1; i += 1024)
        atomicAdd(&lh[binned[i].x & 1023u], 1);
    __syncthreads();

    // exclusive scan of lh over 1024
    int v = lh[t];
    sdata[t] = v;
    __syncthreads();
    for (int off = 1; off < 1024; off <<= 1) {
        int x = (t >= off) ? sdata[t - off] : 0;
        __syncthreads();
        sdata[t] += x;
        __syncthreads();
    }
    const int start = s0 + sdata[t] - v;   // global CSR start for node nb+t
    if (nb + t < N_NODES) cursor[nb + t] = start;
    lh[t] = start;                          // running cursor
    __syncthreads();

    for (int i = s0 + t; i < s1; i += 1024) {
        uint2 e = binned[i];
        int ln = (int)(e.x & 1023u);
        int p = atomicAdd(&lh[ln], 1);
        adj[p] = make_uint2(e.x >> 10, e.y);
    }
}

// ---------------------------------------------------------------------------
// K3: fused aggregate + layernorm + residual (bf16 emb state)
// 4 edge-slot groups of 16 lanes; lane covers 4 cols (ushort4 per gather).
// adj is a one-shot stream -> nt loads keep L2 for the emb table.
// ---------------------------------------------------------------------------
__global__ __launch_bounds__(256) void agg_ln_k(
    const unsigned short* __restrict__ emb_in,
    unsigned short* __restrict__ emb_out,
    float* __restrict__ acc_items,
    const int* __restrict__ cursor, const uint2* __restrict__ adj)
{
    const int n = blockIdx.x * 4 + (threadIdx.x >> 6);   // 37500 blocks exact
    const int lane = threadIdx.x & 63;
    const int g = lane >> 4;          // edge-slot group 0..3
    const int q = lane & 15;          // column quad: cols 4q..4q+3
    const int qo = q << 2;

    const int beg = cursor[n];
    const int end = (n == N_NODES - 1) ? N_EDGES_C : cursor[n + 1];

    float a0 = 0.f, a1 = 0.f, a2 = 0.f, a3 = 0.f;

    int j = beg;
    // main: 32 edges per iteration (8 chunks of 4)
    for (; j + 31 < end; j += 32) {
        uint2 e0 = ntld_u2(&adj[j      + g]);
        uint2 e1 = ntld_u2(&adj[j +  4 + g]);
        uint2 e2 = ntld_u2(&adj[j +  8 + g]);
        uint2 e3 = ntld_u2(&adj[j + 12 + g]);
        uint2 e4 = ntld_u2(&adj[j + 16 + g]);
        uint2 e5 = ntld_u2(&adj[j + 20 + g]);
        uint2 e6 = ntld_u2(&adj[j + 24 + g]);
        uint2 e7 = ntld_u2(&adj[j + 28 + g]);
        ushort4 r0 = *reinterpret_cast<const ushort4*>(emb_in + (size_t)e0.x * DD + qo);
        ushort4 r1 = *reinterpret_cast<const ushort4*>(emb_in + (size_t)e1.x * DD + qo);
        ushort4 r2 = *reinterpret_cast<const ushort4*>(emb_in + (size_t)e2.x * DD + qo);
        ushort4 r3 = *reinterpret_cast<const ushort4*>(emb_in + (size_t)e3.x * DD + qo);
        ushort4 r4 = *reinterpret_cast<const ushort4*>(emb_in + (size_t)e4.x * DD + qo);
        ushort4 r5 = *reinterpret_cast<const ushort4*>(emb_in + (size_t)e5.x * DD + qo);
        ushort4 r6 = *reinterpret_cast<const ushort4*>(emb_in + (size_t)e6.x * DD + qo);
        ushort4 r7 = *reinterpret_cast<const ushort4*>(emb_in + (size_t)e7.x * DD + qo);
        float w0 = __uint_as_float(e0.y), w1 = __uint_as_float(e1.y);
        float w2 = __uint_as_float(e2.y), w3 = __uint_as_float(e3.y);
        float w4 = __uint_as_float(e4.y), w5 = __uint_as_float(e5.y);
        float w6 = __uint_as_float(e6.y), w7 = __uint_as_float(e7.y);
        a0 += w0 * b2f(r0.x); a1 += w0 * b2f(r0.y); a2 += w0 * b2f(r0.z); a3 += w0 * b2f(r0.w);
        a0 += w1 * b2f(r1.x); a1 += w1 * b2f(r1.y); a2 += w1 * b2f(r1.z); a3 += w1 * b2f(r1.w);
        a0 += w2 * b2f(r2.x); a1 += w2 * b2f(r2.y); a2 += w2 * b2f(r2.z); a3 += w2 * b2f(r2.w);
        a0 += w3 * b2f(r3.x); a1 += w3 * b2f(r3.y); a2 += w3 * b2f(r3.z); a3 += w3 * b2f(r3.w);
        a0 += w4 * b2f(r4.x); a1 += w4 * b2f(r4.y); a2 += w4 * b2f(r4.z); a3 += w4 * b2f(r4.w);
        a0 += w5 * b2f(r5.x); a1 += w5 * b2f(r5.y); a2 += w5 * b2f(r5.z); a3 += w5 * b2f(r5.w);
        a0 += w6 * b2f(r6.x); a1 += w6 * b2f(r6.y); a2 += w6 * b2f(r6.z); a3 += w6 * b2f(r6.w);
        a0 += w7 * b2f(r7.x); a1 += w7 * b2f(r7.y); a2 += w7 * b2f(r7.z); a3 += w7 * b2f(r7.w);
    }
    // 16-edge chunk
    if (j + 15 < end) {
        uint2 e0 = ntld_u2(&adj[j + g]);
        uint2 e1 = ntld_u2(&adj[j + 4 + g]);
        uint2 e2 = ntld_u2(&adj[j + 8 + g]);
        uint2 e3 = ntld_u2(&adj[j + 12 + g]);
        ushort4 r0 = *reinterpret_cast<const ushort4*>(emb_in + (size_t)e0.x * DD + qo);
        ushort4 r1 = *reinterpret_cast<const ushort4*>(emb_in + (size_t)e1.x * DD + qo);
        ushort4 r2 = *reinterpret_cast<const ushort4*>(emb_in + (size_t)e2.x * DD + qo);
        ushort4 r3 = *reinterpret_cast<const ushort4*>(emb_in + (size_t)e3.x * DD + qo);
        float w0 = __uint_as_float(e0.y), w1 = __uint_as_float(e1.y);
        float w2 = __uint_as_float(e2.y), w3 = __uint_as_float(e3.y);
        a0 += w0 * b2f(r0.x); a1 += w0 * b2f(r0.y); a2 += w0 * b2f(r0.z); a3 += w0 * b2f(r0.w);
        a0 += w1 * b2f(r1.x); a1 += w1 * b2f(r1.y); a2 += w1 * b2f(r1.z); a3 += w1 * b2f(r1.w);
        a0 += w2 * b2f(r2.x); a1 += w2 * b2f(r2.y); a2 += w2 * b2f(r2.z); a3 += w2 * b2f(r2.w);
        a0 += w3 * b2f(r3.x); a1 += w3 * b2f(r3.y); a2 += w3 * b2f(r3.z); a3 += w3 * b2f(r3.w);
        j += 16;
    }
    // 4-edge chunks
    for (; j + 3 < end; j += 4) {
        uint2 e = ntld_u2(&adj[j + g]);
        ushort4 r = *reinterpret_cast<const ushort4*>(emb_in + (size_t)e.x * DD + qo);
        float w = __uint_as_float(e.y);
        a0 += w * b2f(r.x); a1 += w * b2f(r.y); a2 += w * b2f(r.z); a3 += w * b2f(r.w);
    }
    // tail (<4 edges): group g handles edge j+g if in range
    if (g < end - j) {
        uint2 e = ntld_u2(&adj[j + g]);
        ushort4 r = *reinterpret_cast<const ushort4*>(emb_in + (size_t)e.x * DD + qo);
        float w = __uint_as_float(e.y);
        a0 += w * b2f(r.x); a1 += w * b2f(r.y); a2 += w * b2f(r.z); a3 += w * b2f(r.w);
    }

    // cross-group reduce: lanes {l, l^16, l^32, l^48} hold disjoint edge subsets
    a0 += __shfl_xor(a0, 16); a0 += __shfl_xor(a0, 32);
    a1 += __shfl_xor(a1, 16); a1 += __shfl_xor(a1, 32);
    a2 += __shfl_xor(a2, 16); a2 += __shfl_xor(a2, 32);
    a3 += __shfl_xor(a3, 16); a3 += __shfl_xor(a3, 32);

    // LN reductions over the 16 column-quads (replicated across groups)
    float s = a0 + a1 + a2 + a3;
    s += __shfl_xor(s, 1); s += __shfl_xor(s, 2);
    s += __shfl_xor(s, 4); s += __shfl_xor(s, 8);
    const float m = s * (1.f / 64.f);
    const float d0 = a0 - m, d1 = a1 - m, d2 = a2 - m, d3 = a3 - m;
    float vv = d0 * d0 + d1 * d1 + d2 * d2 + d3 * d3;
    vv += __shfl_xor(vv, 1); vv += __shfl_xor(vv, 2);
    vv += __shfl_xor(vv, 4); vv += __shfl_xor(vv, 8);
    const float rstd = rsqrtf(vv * (1.f / 64.f) + LN_EPS);

    // residual + write (group 0 only: avoids 4x duplicate stores)
    if (g == 0) {
        const size_t o = (size_t)n * DD + qo;
        ushort4 own = *reinterpret_cast<const ushort4*>(emb_in + o);
        float e0 = d0 * rstd + b2f(own.x);
        float e1 = d1 * rstd + b2f(own.y);
        float e2 = d2 * rstd + b2f(own.z);
        float e3 = d3 * rstd + b2f(own.w);
        ushort4 ob;
        ob.x = f2b(e0); ob.y = f2b(e1); ob.z = f2b(e2); ob.w = f2b(e3);
        *reinterpret_cast<ushort4*>(emb_out + o) = ob;
        if (n >= N_USERS) {
            float4* ap = reinterpret_cast<float4*>(
                acc_items + (size_t)(n - N_USERS) * DD + qo);
            float4 v = *ap;
            v.x += e0; v.y += e1; v.z += e2; v.w += e3;
            *ap = v;
        }
    }
}

// ---------------------------------------------------------------------------
// K4: accumulate sampled rows directly into out
// ---------------------------------------------------------------------------
__global__ __launch_bounds__(256) void gather_acc_k(
    const int* __restrict__ users, const int* __restrict__ pos,
    const int* __restrict__ neg, const unsigned short* __restrict__ emb_state,
    float* __restrict__ out, int init)
{
    int gid = blockIdx.x * 256 + threadIdx.x;   // 3*BATCH*DD = 786432
    int part = gid / (BATCH * DD);
    int r = gid - part * (BATCH * DD);
    int b = r >> 6, c = r & 63;
    int node;
    if (part == 0)      node = users[b];
    else if (part == 1) node = N_USERS + pos[b];
    else                node = N_USERS + neg[b];
    float v = b2f(emb_state[(size_t)node * DD + c]);
    if (init) out[gid] = v;
    else      out[gid] += v;
}

// ---------------------------------------------------------------------------
// K5: content loss
// ---------------------------------------------------------------------------
__global__ __launch_bounds__(256) void loss_k(
    const float* __restrict__ acc_items, const float* __restrict__ ic,
    float* __restrict__ loss_slot)
{
    const int total = N_ITEMS * DD;
    int stride = gridDim.x * 256;
    float p = 0.f;
    for (int i = blockIdx.x * 256 + threadIdx.x; i < total; i += stride) {
        float d = __builtin_nontemporal_load(acc_items + i) * 0.25f
                - __builtin_nontemporal_load(ic + i);
        p += d * d;
    }
    #pragma unroll
    for (int off = 32; off; off >>= 1) p += __shfl_xor(p, off);
    __shared__ float red[4];
    if ((threadIdx.x & 63) == 0) red[threadIdx.x >> 6] = p;
    __syncthreads();
    if (threadIdx.x == 0)
        atomicAdd(loss_slot, red[0] + red[1] + red[2] + red[3]);
}

// ---------------------------------------------------------------------------
// K6: out *= 0.25 ; write loss element
// ---------------------------------------------------------------------------
__global__ __launch_bounds__(256) void final_out_k(
    const float* __restrict__ loss_slot, float* __restrict__ out)
{
    int gid = blockIdx.x * 256 + threadIdx.x;
    out[gid] *= 0.25f;
    if (gid == 0)
        out[3 * BATCH * DD] =
            loss_slot[0] * (CONTENT_LOSS_W / (float)(N_ITEMS * DD));
}

// ---------------------------------------------------------------------------
extern "C" void kernel_launch(void* const* d_in, const int* in_sizes, int n_in,
                              void* d_out, int out_size, void* d_ws, size_t ws_size,
                              hipStream_t stream)
{
    const int* users = (const int*)d_in[0];
    const int* pos   = (const int*)d_in[1];
    const int* neg   = (const int*)d_in[2];
    const int* es    = (const int*)d_in[3];
    const int* ed    = (const int*)d_in[4];
    const float* ew  = (const float*)d_in[5];
    const float* ue  = (const float*)d_in[6];
    const float* ie  = (const float*)d_in[7];
    const float* cf  = (const float*)d_in[8];
    const float* Wp  = (const float*)d_in[9];
    const float* bp  = (const float*)d_in[10];
    const float* wg  = (const float*)d_in[11];
    const float* bg  = (const float*)d_in[12];
    float* out = (float*)d_out;

    // ---- workspace layout (~103 MB) ----
    unsigned short* embA = (unsigned short*)d_ws;             // 19.2 MB
    unsigned short* embB = embA + (size_t)N_NODES * DD;       // 19.2 MB
    float* acc_items = (float*)(embB + (size_t)N_NODES * DD); // 12.8 MB
    float* ic        = acc_items + (size_t)N_ITEMS * DD;      // 12.8 MB
    float* loss_slot = ic + (size_t)N_ITEMS * DD;             // 64 B
    int*   cursor    = (int*)(loss_slot + 16);                // 600 KB
    int*   bucket_cnt    = cursor + 150016;                   // 1 KB
    int*   bucket_base   = bucket_cnt + 256;                  // 1 KB
    int*   bucket_cursor = bucket_base + 256;                 // 1 KB
    uint2* adj       = (uint2*)(bucket_cursor + 256);         // 38.4 MB
    // binned scratch overlaps embB..ic (dead after scatter_k; CSR build
    // runs BEFORE content path / embB use). 38.4 MB <= 44.8 MB region.
    uint2* binned    = (uint2*)embB;
    // bstg (96 KB) parked in embA's USER region: content_mfma_k reads it
    // while writing only the ITEM region of embA; init_users_k overwrites
    // it afterwards (bstg dead by then). Zero workspace growth.
    unsigned short* bstg = embA;

    hipMemsetAsync(bucket_cnt, 0, 256 * sizeof(int), stream);
    hipMemsetAsync(loss_slot, 0, sizeof(float), stream);

    // ---- CSR build (no fine-grained global atomics anywhere) ----
    bucket_hist_k<<<HIST_BLKS, 256, 0, stream>>>(ed, bucket_cnt);
    bucket_scan_k<<<1, 256, 0, stream>>>(bucket_cnt, bucket_base, bucket_cursor);
    bin_k<<<(N_EDGES_C + BIN_TILE - 1) / BIN_TILE, 256, 0, stream>>>(
        ed, es, ew, bucket_cursor, binned);
    scatter_k<<<NBUCK, 1024, 0, stream>>>(binned, bucket_base, cursor, adj);

    // ---- content path (MFMA), then user init overwrites bstg ----
    wp_stage_k<<<192, 256, 0, stream>>>(Wp, bstg);
    content_mfma_k<<<(N_ITEMS / 16 + 3) / 4, 256, 0, stream>>>(
        cf, bstg, bp, wg, bg, ie, ic, embA, acc_items);
    init_users_k<<<(N_USERS * DD / 4) / 256, 256, 0, stream>>>(ue, embA);
    gather_acc_k<<<3 * BATCH * DD / 256, 256, 0, stream>>>(users, pos, neg,
                                                           embA, out, 1);

    // 3 propagation layers, ping-pong
    unsigned short* cur = embA;
    unsigned short* nxt = embB;
    for (int l = 0; l < 3; ++l) {
        agg_ln_k<<<N_NODES / 4, 256, 0, stream>>>(cur, nxt, acc_items,
                                                  cursor, adj);
        gather_acc_k<<<3 * BATCH * DD / 256, 256, 0, stream>>>(users, pos, neg,
                                                               nxt, out, 0);
        unsigned short* t = cur; cur = nxt; nxt = t;
    }

    loss_k<<<2048, 256, 0, stream>>>(acc_items, ic, loss_slot);
    final_out_k<<<3 * BATCH * DD / 256, 256, 0, stream>>>(loss_slot, out);
}

// Round 8
// 808.205 us; speedup vs baseline: 1.2728x; 1.0925x over previous
//
#include <hip/hip_runtime.h>
#include <hip/hip_bf16.h>

#define N_USERS 100000
#define N_ITEMS 50000
#define N_NODES 150000
#define DD 64
#define FF 768
#define N_EDGES_C 4800000
#define BATCH 4096
#define LN_EPS 1e-5f
#define CONTENT_LOSS_W 0.1f

#define NBUCK 147       // ceil(150000/1024) - 1024-node buckets
#define BIN_TILE 4096
#define HIST_BLKS 1200
#define INIT_BLKS 6250  // N_USERS*DD/4/256

#define KWIN 24         // 768 / 32 K-windows

typedef __attribute__((ext_vector_type(8))) short short8;
typedef __attribute__((ext_vector_type(4))) float f32x4;

__device__ inline float b2f(unsigned short v) {
    union { unsigned int i; float f; } u;
    u.i = ((unsigned int)v) << 16;
    return u.f;
}
__device__ inline unsigned short f2b(float f) {
    union { float f; unsigned int i; } u; u.f = f;
    unsigned int r = u.i + 0x7fff + ((u.i >> 16) & 1);   // RNE
    return (unsigned short)(r >> 16);
}
__device__ inline short bfc(float f) {
    __hip_bfloat16 h = __float2bfloat16(f);   // compiler emits v_cvt_pk_bf16_f32
    return *reinterpret_cast<short*>(&h);
}

// NT policy (R5/R6 lessons):
//  - nt STORES on scattered/partial-line data: NEVER (defeats L2 write-combine,
//    4x write amplification - R5 scatter_k 196us).
//  - nt LOADS only on strictly single-touch streams (bin's ed/es/ew, mfma's cf).
//    NOT on agg's adj: 4 lane-groups share cache lines -> nt refetches (+16us, R6).

// ---------------------------------------------------------------------------
// prep_k: fused bucket histogram (blocks [0,HIST_BLKS)) + user emb init
// (blocks [HIST_BLKS, HIST_BLKS+INIT_BLKS)).  Independent work, one launch.
// ---------------------------------------------------------------------------
__global__ __launch_bounds__(256) void prep_k(
    const int* __restrict__ ed, int* __restrict__ bucket_cnt,
    const float* __restrict__ ue, unsigned short* __restrict__ emb)
{
    __shared__ int lh[NBUCK];
    if (blockIdx.x < HIST_BLKS) {
        for (int i = threadIdx.x; i < NBUCK; i += 256) lh[i] = 0;
        __syncthreads();
        const int stride = HIST_BLKS * 256;
        for (int t = blockIdx.x * 256 + threadIdx.x; t < N_EDGES_C / 4; t += stride) {
            int4 d = reinterpret_cast<const int4*>(ed)[t];
            atomicAdd(&lh[d.x >> 10], 1);
            atomicAdd(&lh[d.y >> 10], 1);
            atomicAdd(&lh[d.z >> 10], 1);
            atomicAdd(&lh[d.w >> 10], 1);
        }
        __syncthreads();
        for (int i = threadIdx.x; i < NBUCK; i += 256) {
            int c = lh[i];
            if (c) atomicAdd(&bucket_cnt[i], c);
        }
    } else {
        int gid = (blockIdx.x - HIST_BLKS) * 256 + threadIdx.x;
        size_t base = (size_t)gid * 4;
        float4 v = *reinterpret_cast<const float4*>(ue + base);
        ushort4 o;
        o.x = f2b(v.x); o.y = f2b(v.y); o.z = f2b(v.z); o.w = f2b(v.w);
        *reinterpret_cast<ushort4*>(emb + base) = o;
    }
}

// ---------------------------------------------------------------------------
// Wp (f32 [768][64]) -> bf16 B-fragment-staged layout for mfma 16x16x32.
// Runs AFTER scatter_k (bstg lives in the then-dead binned region).
// ---------------------------------------------------------------------------
__global__ __launch_bounds__(256) void wp_stage_k(
    const float* __restrict__ Wp, unsigned short* __restrict__ bstg)
{
    int tid = blockIdx.x * 256 + threadIdx.x;   // 49152 threads
    int e    = tid & 7;
    int lane = (tid >> 3) & 63;
    int nt   = (tid >> 9) & 3;
    int kw   = tid >> 11;
    int k = kw * 32 + ((lane >> 4) << 3) + e;
    int n = nt * 16 + (lane & 15);
    bstg[tid] = (unsigned short)bfc(Wp[k * DD + n]);
}

// ---------------------------------------------------------------------------
// K2: content projection (bf16 MFMA) + f32 gate + combine.  Zero LDS.
// cf is a 153.6 MB one-shot stream -> non-temporal loads.
// ---------------------------------------------------------------------------
__global__ __launch_bounds__(256) void content_mfma_k(
    const float* __restrict__ cf, const unsigned short* __restrict__ bstg,
    const float* __restrict__ bp, const float* __restrict__ wg,
    const float* __restrict__ bg, const float* __restrict__ item_emb,
    float* __restrict__ items_content,
    unsigned short* __restrict__ emb, float* __restrict__ acc_items)
{
    const int wt = blockIdx.x * 4 + (threadIdx.x >> 6);
    if (wt >= N_ITEMS / 16) return;
    const int lane = threadIdx.x & 63;
    const int row0 = wt * 16;

    const int lrow = lane & 15;          // row within tile (A operand)
    const int kgrp = lane >> 4;          // k-chunk 0..3

    const float* aptr = cf + (size_t)(row0 + lrow) * FF + (kgrp << 3);
    const float* wptr = wg + (kgrp << 3);
    const short8* bptr = reinterpret_cast<const short8*>(bstg) + lane;

    f32x4 acc0 = {0.f, 0.f, 0.f, 0.f};
    f32x4 acc1 = {0.f, 0.f, 0.f, 0.f};
    f32x4 acc2 = {0.f, 0.f, 0.f, 0.f};
    f32x4 acc3 = {0.f, 0.f, 0.f, 0.f};
    float gp = 0.f;

    #pragma unroll 4
    for (int kw = 0; kw < KWIN; ++kw) {
        f32x4 a0 = __builtin_nontemporal_load(
            reinterpret_cast<const f32x4*>(aptr + kw * 32));
        f32x4 a1 = __builtin_nontemporal_load(
            reinterpret_cast<const f32x4*>(aptr + kw * 32 + 4));
        float4 w0 = *reinterpret_cast<const float4*>(wptr + kw * 32);
        float4 w1 = *reinterpret_cast<const float4*>(wptr + kw * 32 + 4);

        gp += a0[0] * w0.x + a0[1] * w0.y + a0[2] * w0.z + a0[3] * w0.w;
        gp += a1[0] * w1.x + a1[1] * w1.y + a1[2] * w1.z + a1[3] * w1.w;

        short8 af;
        af[0] = bfc(a0[0]); af[1] = bfc(a0[1]); af[2] = bfc(a0[2]); af[3] = bfc(a0[3]);
        af[4] = bfc(a1[0]); af[5] = bfc(a1[1]); af[6] = bfc(a1[2]); af[7] = bfc(a1[3]);

        const short8* bb = bptr + (size_t)kw * 256;   // (kw*4+nt)*64+lane
        short8 b0 = bb[0];
        short8 b1 = bb[64];
        short8 b2 = bb[128];
        short8 b3 = bb[192];

        acc0 = __builtin_amdgcn_mfma_f32_16x16x32_bf16(af, b0, acc0, 0, 0, 0);
        acc1 = __builtin_amdgcn_mfma_f32_16x16x32_bf16(af, b1, acc1, 0, 0, 0);
        acc2 = __builtin_amdgcn_mfma_f32_16x16x32_bf16(af, b2, acc2, 0, 0, 0);
        acc3 = __builtin_amdgcn_mfma_f32_16x16x32_bf16(af, b3, acc3, 0, 0, 0);
    }

    // gate: lanes {l, l^16, l^32, l^48} hold k-partials for row lane&15
    gp += __shfl_xor(gp, 16);
    gp += __shfl_xor(gp, 32);
    const float g = 1.f / (1.f + __expf(-(gp + bg[0])));

    // epilogue: C layout col=lane&15, row=(lane>>4)*4+reg
    const int rbase = kgrp << 2;
    f32x4 accs[4] = {acc0, acc1, acc2, acc3};
    #pragma unroll
    for (int nt = 0; nt < 4; ++nt) {
        const int col = nt * 16 + lrow;
        const float bpv = bp[col];
        #pragma unroll
        for (int r = 0; r < 4; ++r) {
            const int rit = rbase + r;
            const int row = row0 + rit;
            const float icv = accs[nt][r] + bpv;
            const float gr = __shfl(g, rit);
            const size_t o = (size_t)row * DD + col;
            const float ie = __builtin_nontemporal_load(item_emb + o);
            const float it = (1.f - gr) * ie + gr * icv;
            items_content[o] = icv;
            emb[(size_t)(N_USERS + row) * DD + col] = f2b(it);
            acc_items[o] = it;
        }
    }
}

// single block: exclusive scan of 147 bucket counts -> bucket_base[148],
// and init bucket_cursor = base.
__global__ __launch_bounds__(256) void bucket_scan_k(
    const int* __restrict__ bucket_cnt, int* __restrict__ bucket_base,
    int* __restrict__ bucket_cursor)
{
    __shared__ int sdata[256];
    int t = threadIdx.x;
    int v = (t < NBUCK) ? bucket_cnt[t] : 0;
    sdata[t] = v;
    __syncthreads();
    for (int off = 1; off < 256; off <<= 1) {
        int x = (t >= off) ? sdata[t - off] : 0;
        __syncthreads();
        sdata[t] += x;
        __syncthreads();
    }
    if (t < NBUCK) {
        int b = sdata[t] - v;   // exclusive
        bucket_base[t] = b;
        bucket_cursor[t] = b;
    }
    if (t == NBUCK - 1) bucket_base[NBUCK] = sdata[t];   // == N_EDGES_C
}

// Pass A: tile-sort edges into 147 coarse buckets with LDS write combining.
// binned entry: x = (src<<10)|(dst&1023), y = weight bits
// copy-out uses a per-staged-entry bucket-id byte (O(1) lookup).
// PLAIN stores (L2 write-combining essential).
__global__ __launch_bounds__(256) void bin_k(
    const int* __restrict__ ed, const int* __restrict__ es,
    const float* __restrict__ ew, int* __restrict__ bucket_cursor,
    uint2* __restrict__ binned)
{
    __shared__ uint2 stage[BIN_TILE];        // 32 KB
    __shared__ unsigned char bktb[BIN_TILE]; // 4 KB bucket id per staged slot
    __shared__ int h[NBUCK];                 // hist, then running cursor
    __shared__ int o[NBUCK];                 // exclusive offsets
    __shared__ int gbase[NBUCK];
    __shared__ int scanbuf[256];

    const int t = threadIdx.x;
    const int base = blockIdx.x * BIN_TILE;
    const int cnt = min(BIN_TILE, N_EDGES_C - base);

    for (int i = t; i < NBUCK; i += 256) h[i] = 0;
    __syncthreads();

    int ld[16]; int ls[16]; float lw[16]; int lb[16];
    #pragma unroll
    for (int k = 0; k < 16; ++k) {
        int i = t + k * 256;
        if (i < cnt) {
            int d = __builtin_nontemporal_load(ed + base + i);
            ld[k] = d;
            ls[k] = __builtin_nontemporal_load(es + base + i);
            lw[k] = __builtin_nontemporal_load(ew + base + i);
            int b = d >> 10;
            lb[k] = b;
            atomicAdd(&h[b], 1);
        } else lb[k] = -1;
    }
    __syncthreads();

    // exclusive scan of h -> o (NBUCK <= 256)
    {
        int v = (t < NBUCK) ? h[t] : 0;
        scanbuf[t] = v;
        __syncthreads();
        for (int off = 1; off < 256; off <<= 1) {
            int x = (t >= off) ? scanbuf[t - off] : 0;
            __syncthreads();
            scanbuf[t] += x;
            __syncthreads();
        }
        if (t < NBUCK) o[t] = scanbuf[t] - v;
    }
    __syncthreads();

    if (t < NBUCK) h[t] = o[t];   // running cursors
    __syncthreads();

    #pragma unroll
    for (int k = 0; k < 16; ++k) {
        if (lb[k] >= 0) {
            int p = atomicAdd(&h[lb[k]], 1);
            unsigned key = ((unsigned)ls[k] << 10) | (unsigned)(ld[k] & 1023);
            stage[p] = make_uint2(key, __float_as_uint(lw[k]));
            bktb[p] = (unsigned char)lb[k];
        }
    }
    __syncthreads();

    // reserve contiguous global space per bucket (h now = end offsets)
    if (t < NBUCK) {
        int c = h[t] - o[t];
        gbase[t] = (c > 0) ? atomicAdd(&bucket_cursor[t], c) : 0;
    }
    __syncthreads();

    // copy out, coalesced within bucket segments; O(1) bucket lookup
    for (int i = t; i < cnt; i += 256) {
        int b = bktb[i];
        binned[gbase[b] + (i - o[b])] = stage[i];
    }
}

// Pass B: one block owns one 1024-node bucket.  Per-node histogram from its
// binned segment, shuffle-based scan (3 barriers vs 20), emits cursor[],
// then scatters.  PLAIN adj stores (owning XCD's L2 combines them).
__global__ __launch_bounds__(1024) void scatter_k(
    const uint2* __restrict__ binned, const int* __restrict__ bucket_base,
    int* __restrict__ cursor, uint2* __restrict__ adj)
{
    __shared__ int lh[1024];     // hist -> running cursor
    __shared__ int wsum[16];     // per-wave partial sums
    const int b = blockIdx.x;
    const int t = threadIdx.x;
    const int lane = t & 63;
    const int wid = t >> 6;
    const int nb = b << 10;
    const int s0 = bucket_base[b];
    const int s1 = bucket_base[b + 1];

    lh[t] = 0;
    __syncthreads();
    for (int i = s0 + t; i < s1; i += 1024)
        atomicAdd(&lh[binned[i].x & 1023u], 1);
    __syncthreads();

    // shuffle-based exclusive scan of lh over 1024
    const int v = lh[t];
    int x = v;
    #pragma unroll
    for (int off = 1; off < 64; off <<= 1) {
        int y = __shfl_up(x, off);
        if (lane >= off) x += y;
    }                                   // x = inclusive scan within wave
    if (lane == 63) wsum[wid] = x;
    __syncthreads();
    if (wid == 0 && lane < 16) {
        int w = wsum[lane];
        #pragma unroll
        for (int off = 1; off < 16; off <<= 1) {
            int y = __shfl_up(w, off);
            if (lane >= off) w += y;
        }
        wsum[lane] = w;                 // inclusive wave-sum scan
    }
    __syncthreads();
    const int wbase = (wid > 0) ? wsum[wid - 1] : 0;
    const int start = s0 + wbase + (x - v);   // global CSR start for node nb+t
    if (nb + t < N_NODES) cursor[nb + t] = start;
    lh[t] = start;                      // running cursor
    __syncthreads();

    for (int i = s0 + t; i < s1; i += 1024) {
        uint2 e = binned[i];
        int ln = (int)(e.x & 1023u);
        int p = atomicAdd(&lh[ln], 1);
        adj[p] = make_uint2(e.x >> 10, e.y);
    }
}

// ---------------------------------------------------------------------------
// K3: fused aggregate + layernorm + residual (bf16 emb state)
// 4 edge-slot groups of 16 lanes; lane covers 4 cols (ushort4 per gather).
// PLAIN adj loads (groups share cache lines - R6 lesson).  At the random-
// access fabric ceiling (~2.8 TB/s, MLP-insensitive per R4) - do not touch.
// ---------------------------------------------------------------------------
__global__ __launch_bounds__(256) void agg_ln_k(
    const unsigned short* __restrict__ emb_in,
    unsigned short* __restrict__ emb_out,
    float* __restrict__ acc_items,
    const int* __restrict__ cursor, const uint2* __restrict__ adj)
{
    const int n = blockIdx.x * 4 + (threadIdx.x >> 6);   // 37500 blocks exact
    const int lane = threadIdx.x & 63;
    const int g = lane >> 4;          // edge-slot group 0..3
    const int q = lane & 15;          // column quad: cols 4q..4q+3
    const int qo = q << 2;

    const int beg = cursor[n];
    const int end = (n == N_NODES - 1) ? N_EDGES_C : cursor[n + 1];

    float a0 = 0.f, a1 = 0.f, a2 = 0.f, a3 = 0.f;

    int j = beg;
    // main: 32 edges per iteration (8 chunks of 4)
    for (; j + 31 < end; j += 32) {
        uint2 e0 = adj[j      + g];
        uint2 e1 = adj[j +  4 + g];
        uint2 e2 = adj[j +  8 + g];
        uint2 e3 = adj[j + 12 + g];
        uint2 e4 = adj[j + 16 + g];
        uint2 e5 = adj[j + 20 + g];
        uint2 e6 = adj[j + 24 + g];
        uint2 e7 = adj[j + 28 + g];
        ushort4 r0 = *reinterpret_cast<const ushort4*>(emb_in + (size_t)e0.x * DD + qo);
        ushort4 r1 = *reinterpret_cast<const ushort4*>(emb_in + (size_t)e1.x * DD + qo);
        ushort4 r2 = *reinterpret_cast<const ushort4*>(emb_in + (size_t)e2.x * DD + qo);
        ushort4 r3 = *reinterpret_cast<const ushort4*>(emb_in + (size_t)e3.x * DD + qo);
        ushort4 r4 = *reinterpret_cast<const ushort4*>(emb_in + (size_t)e4.x * DD + qo);
        ushort4 r5 = *reinterpret_cast<const ushort4*>(emb_in + (size_t)e5.x * DD + qo);
        ushort4 r6 = *reinterpret_cast<const ushort4*>(emb_in + (size_t)e6.x * DD + qo);
        ushort4 r7 = *reinterpret_cast<const ushort4*>(emb_in + (size_t)e7.x * DD + qo);
        float w0 = __uint_as_float(e0.y), w1 = __uint_as_float(e1.y);
        float w2 = __uint_as_float(e2.y), w3 = __uint_as_float(e3.y);
        float w4 = __uint_as_float(e4.y), w5 = __uint_as_float(e5.y);
        float w6 = __uint_as_float(e6.y), w7 = __uint_as_float(e7.y);
        a0 += w0 * b2f(r0.x); a1 += w0 * b2f(r0.y); a2 += w0 * b2f(r0.z); a3 += w0 * b2f(r0.w);
        a0 += w1 * b2f(r1.x); a1 += w1 * b2f(r1.y); a2 += w1 * b2f(r1.z); a3 += w1 * b2f(r1.w);
        a0 += w2 * b2f(r2.x); a1 += w2 * b2f(r2.y); a2 += w2 * b2f(r2.z); a3 += w2 * b2f(r2.w);
        a0 += w3 * b2f(r3.x); a1 += w3 * b2f(r3.y); a2 += w3 * b2f(r3.z); a3 += w3 * b2f(r3.w);
        a0 += w4 * b2f(r4.x); a1 += w4 * b2f(r4.y); a2 += w4 * b2f(r4.z); a3 += w4 * b2f(r4.w);
        a0 += w5 * b2f(r5.x); a1 += w5 * b2f(r5.y); a2 += w5 * b2f(r5.z); a3 += w5 * b2f(r5.w);
        a0 += w6 * b2f(r6.x); a1 += w6 * b2f(r6.y); a2 += w6 * b2f(r6.z); a3 += w6 * b2f(r6.w);
        a0 += w7 * b2f(r7.x); a1 += w7 * b2f(r7.y); a2 += w7 * b2f(r7.z); a3 += w7 * b2f(r7.w);
    }
    // 16-edge chunk
    if (j + 15 < end) {
        uint2 e0 = adj[j + g];
        uint2 e1 = adj[j + 4 + g];
        uint2 e2 = adj[j + 8 + g];
        uint2 e3 = adj[j + 12 + g];
        ushort4 r0 = *reinterpret_cast<const ushort4*>(emb_in + (size_t)e0.x * DD + qo);
        ushort4 r1 = *reinterpret_cast<const ushort4*>(emb_in + (size_t)e1.x * DD + qo);
        ushort4 r2 = *reinterpret_cast<const ushort4*>(emb_in + (size_t)e2.x * DD + qo);
        ushort4 r3 = *reinterpret_cast<const ushort4*>(emb_in + (size_t)e3.x * DD + qo);
        float w0 = __uint_as_float(e0.y), w1 = __uint_as_float(e1.y);
        float w2 = __uint_as_float(e2.y), w3 = __uint_as_float(e3.y);
        a0 += w0 * b2f(r0.x); a1 += w0 * b2f(r0.y); a2 += w0 * b2f(r0.z); a3 += w0 * b2f(r0.w);
        a0 += w1 * b2f(r1.x); a1 += w1 * b2f(r1.y); a2 += w1 * b2f(r1.z); a3 += w1 * b2f(r1.w);
        a0 += w2 * b2f(r2.x); a1 += w2 * b2f(r2.y); a2 += w2 * b2f(r2.z); a3 += w2 * b2f(r2.w);
        a0 += w3 * b2f(r3.x); a1 += w3 * b2f(r3.y); a2 += w3 * b2f(r3.z); a3 += w3 * b2f(r3.w);
        j += 16;
    }
    // 4-edge chunks
    for (; j + 3 < end; j += 4) {
        uint2 e = adj[j + g];
        ushort4 r = *reinterpret_cast<const ushort4*>(emb_in + (size_t)e.x * DD + qo);
        float w = __uint_as_float(e.y);
        a0 += w * b2f(r.x); a1 += w * b2f(r.y); a2 += w * b2f(r.z); a3 += w * b2f(r.w);
    }
    // tail (<4 edges): group g handles edge j+g if in range
    if (g < end - j) {
        uint2 e = adj[j + g];
        ushort4 r = *reinterpret_cast<const ushort4*>(emb_in + (size_t)e.x * DD + qo);
        float w = __uint_as_float(e.y);
        a0 += w * b2f(r.x); a1 += w * b2f(r.y); a2 += w * b2f(r.z); a3 += w * b2f(r.w);
    }

    // cross-group reduce: lanes {l, l^16, l^32, l^48} hold disjoint edge subsets
    a0 += __shfl_xor(a0, 16); a0 += __shfl_xor(a0, 32);
    a1 += __shfl_xor(a1, 16); a1 += __shfl_xor(a1, 32);
    a2 += __shfl_xor(a2, 16); a2 += __shfl_xor(a2, 32);
    a3 += __shfl_xor(a3, 16); a3 += __shfl_xor(a3, 32);

    // LN reductions over the 16 column-quads (replicated across groups)
    float s = a0 + a1 + a2 + a3;
    s += __shfl_xor(s, 1); s += __shfl_xor(s, 2);
    s += __shfl_xor(s, 4); s += __shfl_xor(s, 8);
    const float m = s * (1.f / 64.f);
    const float d0 = a0 - m, d1 = a1 - m, d2 = a2 - m, d3 = a3 - m;
    float vv = d0 * d0 + d1 * d1 + d2 * d2 + d3 * d3;
    vv += __shfl_xor(vv, 1); vv += __shfl_xor(vv, 2);
    vv += __shfl_xor(vv, 4); vv += __shfl_xor(vv, 8);
    const float rstd = rsqrtf(vv * (1.f / 64.f) + LN_EPS);

    // residual + write (group 0 only: avoids 4x duplicate stores)
    if (g == 0) {
        const size_t o = (size_t)n * DD + qo;
        ushort4 own = *reinterpret_cast<const ushort4*>(emb_in + o);
        float e0 = d0 * rstd + b2f(own.x);
        float e1 = d1 * rstd + b2f(own.y);
        float e2 = d2 * rstd + b2f(own.z);
        float e3 = d3 * rstd + b2f(own.w);
        ushort4 ob;
        ob.x = f2b(e0); ob.y = f2b(e1); ob.z = f2b(e2); ob.w = f2b(e3);
        *reinterpret_cast<ushort4*>(emb_out + o) = ob;
        if (n >= N_USERS) {
            float4* ap = reinterpret_cast<float4*>(
                acc_items + (size_t)(n - N_USERS) * DD + qo);
            float4 v = *ap;
            v.x += e0; v.y += e1; v.z += e2; v.w += e3;
            *ap = v;
        }
    }
}

// ---------------------------------------------------------------------------
// K4: accumulate sampled rows directly into out
// ---------------------------------------------------------------------------
__global__ __launch_bounds__(256) void gather_acc_k(
    const int* __restrict__ users, const int* __restrict__ pos,
    const int* __restrict__ neg, const unsigned short* __restrict__ emb_state,
    float* __restrict__ out, int init)
{
    int gid = blockIdx.x * 256 + threadIdx.x;   // 3*BATCH*DD = 786432
    int part = gid / (BATCH * DD);
    int r = gid - part * (BATCH * DD);
    int b = r >> 6, c = r & 63;
    int node;
    if (part == 0)      node = users[b];
    else if (part == 1) node = N_USERS + pos[b];
    else                node = N_USERS + neg[b];
    float v = b2f(emb_state[(size_t)node * DD + c]);
    if (init) out[gid] = v;
    else      out[gid] += v;
}

// ---------------------------------------------------------------------------
// K5: content loss
// ---------------------------------------------------------------------------
__global__ __launch_bounds__(256) void loss_k(
    const float* __restrict__ acc_items, const float* __restrict__ ic,
    float* __restrict__ loss_slot)
{
    const int total = N_ITEMS * DD;
    int stride = gridDim.x * 256;
    float p = 0.f;
    for (int i = blockIdx.x * 256 + threadIdx.x; i < total; i += stride) {
        float d = __builtin_nontemporal_load(acc_items + i) * 0.25f
                - __builtin_nontemporal_load(ic + i);
        p += d * d;
    }
    #pragma unroll
    for (int off = 32; off; off >>= 1) p += __shfl_xor(p, off);
    __shared__ float red[4];
    if ((threadIdx.x & 63) == 0) red[threadIdx.x >> 6] = p;
    __syncthreads();
    if (threadIdx.x == 0)
        atomicAdd(loss_slot, red[0] + red[1] + red[2] + red[3]);
}

// ---------------------------------------------------------------------------
// K6: out *= 0.25 ; write loss element
// ---------------------------------------------------------------------------
__global__ __launch_bounds__(256) void final_out_k(
    const float* __restrict__ loss_slot, float* __restrict__ out)
{
    int gid = blockIdx.x * 256 + threadIdx.x;
    out[gid] *= 0.25f;
    if (gid == 0)
        out[3 * BATCH * DD] =
            loss_slot[0] * (CONTENT_LOSS_W / (float)(N_ITEMS * DD));
}

// ---------------------------------------------------------------------------
extern "C" void kernel_launch(void* const* d_in, const int* in_sizes, int n_in,
                              void* d_out, int out_size, void* d_ws, size_t ws_size,
                              hipStream_t stream)
{
    const int* users = (const int*)d_in[0];
    const int* pos   = (const int*)d_in[1];
    const int* neg   = (const int*)d_in[2];
    const int* es    = (const int*)d_in[3];
    const int* ed    = (const int*)d_in[4];
    const float* ew  = (const float*)d_in[5];
    const float* ue  = (const float*)d_in[6];
    const float* ie  = (const float*)d_in[7];
    const float* cf  = (const float*)d_in[8];
    const float* Wp  = (const float*)d_in[9];
    const float* bp  = (const float*)d_in[10];
    const float* wg  = (const float*)d_in[11];
    const float* bg  = (const float*)d_in[12];
    float* out = (float*)d_out;

    // ---- workspace layout (~103 MB) ----
    unsigned short* embA = (unsigned short*)d_ws;             // 19.2 MB
    unsigned short* embB = embA + (size_t)N_NODES * DD;       // 19.2 MB
    float* acc_items = (float*)(embB + (size_t)N_NODES * DD); // 12.8 MB
    float* ic        = acc_items + (size_t)N_ITEMS * DD;      // 12.8 MB
    float* loss_slot = ic + (size_t)N_ITEMS * DD;             // 64 B
    int*   cursor    = (int*)(loss_slot + 16);                // 600 KB
    int*   bucket_cnt    = cursor + 150016;                   // 1 KB
    int*   bucket_base   = bucket_cnt + 256;                  // 1 KB
    int*   bucket_cursor = bucket_base + 256;                 // 1 KB
    uint2* adj       = (uint2*)(bucket_cursor + 256);         // 38.4 MB
    // binned scratch overlaps embB..ic (dead after scatter_k).
    uint2* binned    = (uint2*)embB;
    // bstg (96 KB) parked at embB start: binned is dead by the time
    // wp_stage_k writes it (after scatter_k); embB itself is first written
    // by layer-0 agg_ln (after content_mfma_k has consumed bstg).
    unsigned short* bstg = embB;

    hipMemsetAsync(bucket_cnt, 0, 256 * sizeof(int), stream);
    hipMemsetAsync(loss_slot, 0, sizeof(float), stream);

    // ---- fused prep: bucket histogram + user emb init (independent) ----
    prep_k<<<HIST_BLKS + INIT_BLKS, 256, 0, stream>>>(ed, bucket_cnt, ue, embA);

    // ---- CSR build (no fine-grained global atomics anywhere) ----
    bucket_scan_k<<<1, 256, 0, stream>>>(bucket_cnt, bucket_base, bucket_cursor);
    bin_k<<<(N_EDGES_C + BIN_TILE - 1) / BIN_TILE, 256, 0, stream>>>(
        ed, es, ew, bucket_cursor, binned);
    scatter_k<<<NBUCK, 1024, 0, stream>>>(binned, bucket_base, cursor, adj);

    // ---- content path (MFMA); bstg lives in now-dead binned region ----
    wp_stage_k<<<192, 256, 0, stream>>>(Wp, bstg);
    content_mfma_k<<<(N_ITEMS / 16 + 3) / 4, 256, 0, stream>>>(
        cf, bstg, bp, wg, bg, ie, ic, embA, acc_items);
    gather_acc_k<<<3 * BATCH * DD / 256, 256, 0, stream>>>(users, pos, neg,
                                                           embA, out, 1);

    // 3 propagation layers, ping-pong
    unsigned short* cur = embA;
    unsigned short* nxt = embB;
    for (int l = 0; l < 3; ++l) {
        agg_ln_k<<<N_NODES / 4, 256, 0, stream>>>(cur, nxt, acc_items,
                                                  cursor, adj);
        gather_acc_k<<<3 * BATCH * DD / 256, 256, 0, stream>>>(users, pos, neg,
                                                               nxt, out, 0);
        unsigned short* t = cur; cur = nxt; nxt = t;
    }

    loss_k<<<2048, 256, 0, stream>>>(acc_items, ic, loss_slot);
    final_out_k<<<3 * BATCH * DD / 256, 256, 0, stream>>>(loss_slot, out);
}